// Round 8
// baseline (1128.271 us; speedup 1.0000x reference)
//
#include <hip/hip_runtime.h>

typedef _Float16 half8  __attribute__((ext_vector_type(8)));
typedef __fp16   fp16x2 __attribute__((ext_vector_type(2)));
typedef float    f32x16 __attribute__((ext_vector_type(16)));
typedef float    f32x4v __attribute__((ext_vector_type(4)));
typedef unsigned uint2v __attribute__((ext_vector_type(2)));

#define NWG     256
#define WGSZ    512
#define CHUNKS  8          // samples per WG = CHUNKS*WGSZ = 4096; grid covers 1048576
// u32 offsets inside static LDS
#define WFRAG0   0         // W2 frags: 8192 u32 (128x128 f16, MFMA A-frag order)
#define WFRAG1   8192      // W3
#define WFRAG2   16384     // W4
#define W1FRAGO  24576     // 1024 u32
#define W5FRAGO  25600     // 2048 u32
#define BIASO    27648     // b1..b4: 4*128 f32
#define B5O      28160     // b5: 2 f32
#define SMEM_U32 28164     // 112656 B static LDS -> 1 WG/CU (2 waves/EU)

__device__ __forceinline__ unsigned pack_rn(float a, float b) {
  unsigned lo = (unsigned)__builtin_bit_cast(unsigned short, (_Float16)a);
  unsigned hi = (unsigned)__builtin_bit_cast(unsigned short, (_Float16)b);
  return lo | (hi << 16);
}
__device__ __forceinline__ unsigned pack_rtz(float a, float b) {
  fp16x2 h = __builtin_amdgcn_cvt_pkrtz(a, b);
  return __builtin_bit_cast(unsigned, h);
}
// swish = v * sigmoid(v) = v * rcp(1 + 2^(-v*log2e)) : 3 VALU + 2 trans
__device__ __forceinline__ float sw(float v) {
  float e = __builtin_amdgcn_exp2f(v * -1.44269504089f);
  return v * __builtin_amdgcn_rcpf(1.0f + e);
}
__device__ __forceinline__ half8 ldfrag(const unsigned* p) {
  uint4 u = *reinterpret_cast<const uint4*>(p);
  return __builtin_bit_cast(half8, u);
}
__device__ __forceinline__ half8 mkfrag(unsigned a, unsigned b, unsigned c, unsigned d) {
  uint4 u = make_uint4(a, b, c, d);
  return __builtin_bit_cast(half8, u);
}

// permlane32_swap(a,b): a'[32+i]<->b[i]; result (a',b') =
//   a' = lanes<32: a       | lanes>=32: b[lane-32]   == (lo? a : shfl_xor(b,32))
//   b' = lanes<32: a[l+32] | lanes>=32: b            == (lo? shfl_xor(a,32) : b)
__device__ __forceinline__ void pl_swap(unsigned &a, unsigned &b) {
#if __has_builtin(__builtin_amdgcn_permlane32_swap)
  uint2v r = __builtin_amdgcn_permlane32_swap(a, b, false, false);
  a = r.x; b = r.y;
#else
  asm("v_permlane32_swap_b32 %0, %1" : "+v"(a), "+v"(b));
#endif
}

// Regroup packed D-frag (source frag ks) into the two B-frags for kk=2ks, 2ks+1.
__device__ __forceinline__ void build_b(const unsigned (&p)[8], half8 &bf0, half8 &bf1) {
  unsigned a0 = p[0], a2 = p[2];
  unsigned a1 = p[1], a3 = p[3];
  unsigned a4 = p[4], a6 = p[6];
  unsigned a5 = p[5], a7 = p[7];
  pl_swap(a0, a2);
  pl_swap(a1, a3);
  pl_swap(a4, a6);
  pl_swap(a5, a7);
  bf0 = mkfrag(a0, a1, a2, a3);
  bf1 = mkfrag(a4, a5, a6, a7);
}

// One 128x128 layer for 32 samples, one output-quarter (mi) at a time.
// Live set: pin(32) + pout(<=24 while building) + acc(16) + bf(8) + temps
// ~= 100 regs -> fits the 128-VGPR budget the RA insists on (r2-r7: every
// attribute spelling left VGPR_Count=128 and spilled ~1.6GB/dispatch).
__device__ __forceinline__ void layer32(const unsigned (&pin)[4][8], unsigned (&pout)[4][8],
                                        const unsigned* wb, const float* bias, int h5, int lane) {
#pragma unroll
  for (int mi = 0; mi < 4; ++mi) {
    f32x16 acc;
    // bias: acc[4g+q] = bias[32mi + 8g + 4h5 + q]  (D-row map (r&3)+8(r>>2)+4h5)
#pragma unroll
    for (int g = 0; g < 4; ++g) {
      f32x4v bv = *reinterpret_cast<const f32x4v*>(bias + 32*mi + 8*g + 4*h5);
#pragma unroll
      for (int q = 0; q < 4; ++q) acc[4*g+q] = bv[q];
    }
#pragma unroll
    for (int ks = 0; ks < 4; ++ks) {
      half8 bf0, bf1;
      build_b(pin[ks], bf0, bf1);
      half8 a0 = ldfrag(wb + (((2*ks  )*4 + mi)*64 + lane)*4);
      acc = __builtin_amdgcn_mfma_f32_32x32x16_f16(a0, bf0, acc, 0, 0, 0);
      half8 a1 = ldfrag(wb + (((2*ks+1)*4 + mi)*64 + lane)*4);
      acc = __builtin_amdgcn_mfma_f32_32x32x16_f16(a1, bf1, acc, 0, 0, 0);
    }
    // swish + pack this quarter's output features
#pragma unroll
    for (int p = 0; p < 8; ++p)
      pout[mi][p] = pack_rtz(sw(acc[2*p]), sw(acc[2*p+1]));
  }
}

extern "C" __global__ __launch_bounds__(WGSZ, 1)
void mlp_k(const float* __restrict__ x, const float* __restrict__ t,
           const float* __restrict__ W1, const float* __restrict__ b1,
           const float* __restrict__ W2, const float* __restrict__ b2,
           const float* __restrict__ W3, const float* __restrict__ b3,
           const float* __restrict__ W4, const float* __restrict__ b4,
           const float* __restrict__ W5, const float* __restrict__ b5p,
           float* __restrict__ out)
{
  __shared__ unsigned smem[SMEM_U32];
  const int tid = threadIdx.x;

  // ---------- stage weights (once per WG) ----------
  // mid layers: slot((kk,mi,lane,j2)) = pack(W[k][c], W[k+1][c]); k=16kk+8(lane>>5)+2j2, c=32mi+(lane&31)
  {
    const float* Wm[3] = {W2, W3, W4};
#pragma unroll
    for (int L = 0; L < 3; ++L) {
      const float* W = Wm[L];
#pragma unroll 1
      for (int it = 0; it < 16; ++it) {
        int i = it*WGSZ + tid;
        int lane = i & 63, j2 = (i >> 6) & 3, mi = (i >> 8) & 3, kk = i >> 10;
        int k = 16*kk + 8*(lane >> 5) + 2*j2;
        int c = 32*mi + (lane & 31);
        smem[L*8192 + ((kk*4 + mi)*64 + lane)*4 + j2] = pack_rn(W[k*128 + c], W[(k+1)*128 + c]);
      }
    }
  }
  // W1 (3x128), K padded to 16
#pragma unroll 1
  for (int it = 0; it < 2; ++it) {
    int i = it*WGSZ + tid;
    int lane = i & 63, j2 = (i >> 6) & 3, mi = (i >> 8) & 3;
    int k = 8*(lane >> 5) + 2*j2;
    int c = 32*mi + (lane & 31);
    float a = (k   < 3) ? W1[k*128 + c]     : 0.f;
    float b = (k+1 < 3) ? W1[(k+1)*128 + c] : 0.f;
    smem[W1FRAGO + (mi*64 + lane)*4 + j2] = pack_rn(a, b);
  }
  // W5 (128x2), M padded to 32 (rows >=2 are zero)
#pragma unroll 1
  for (int it = 0; it < 4; ++it) {
    int i = it*WGSZ + tid;
    int lane = i & 63, j2 = (i >> 6) & 3, kk = (i >> 8) & 7;
    int m = lane & 31;
    int k = 16*kk + 8*(lane >> 5) + 2*j2;
    float a = (m < 2) ? W5[k*2 + m]     : 0.f;
    float b = (m < 2) ? W5[(k+1)*2 + m] : 0.f;
    smem[W5FRAGO + (kk*64 + lane)*4 + j2] = pack_rn(a, b);
  }
  // biases
  {
    const float* bp = (tid < 128) ? b1 : (tid < 256) ? b2 : (tid < 384) ? b3 : b4;
    smem[BIASO + tid] = __builtin_bit_cast(unsigned, bp[tid & 127]);
    if (tid < 2) smem[B5O + tid] = __builtin_bit_cast(unsigned, b5p[tid]);
  }
  __syncthreads();

  // ---------- compute: no further barriers, waves free-run ----------
  const int lane = tid & 63;
  const int wv   = tid >> 6;
  const int h5   = lane >> 5;
  const int col  = lane & 31;
  const bool lo  = lane < 32;
  const float* biasp = reinterpret_cast<const float*>(smem + BIASO);
  const float b50 = reinterpret_cast<const float*>(smem + B5O)[0];
  const float b51 = reinterpret_cast<const float*>(smem + B5O)[1];
  const float2* x2 = reinterpret_cast<const float2*>(x);

  // 16 passes of 32 samples: pk state is 32 regs (vs 64), mid layers run
  // quarter-at-a-time -> worst-point live set ~100 regs, under the 128 cap.
#pragma unroll 1
  for (int ps = 0; ps < CHUNKS*2; ++ps) {
    const int base = ((int)blockIdx.x * CHUNKS + (ps >> 1)) * WGSZ + wv * 64 + 32*(ps & 1);
    const int s = base + col;

    float2 xa = x2[s];
    float  ta = t[s];

    // L1 B-operand: feats {x0,x1,t,0...} only in lanes h5==0, j<3
    half8 b1f = mkfrag(h5 ? 0u : pack_rn(xa.x, xa.y), h5 ? 0u : pack_rn(ta, 0.f), 0u, 0u);

    unsigned pkA[4][8], pkB[4][8];

    // L1: h1^T = W1^T @ [x;t]^T + b1 (quarter-at-a-time)
#pragma unroll
    for (int mi = 0; mi < 4; ++mi) {
      f32x16 acc;
#pragma unroll
      for (int g = 0; g < 4; ++g) {
        f32x4v bv = *reinterpret_cast<const f32x4v*>(biasp + 32*mi + 8*g + 4*h5);
#pragma unroll
        for (int q = 0; q < 4; ++q) acc[4*g+q] = bv[q];
      }
      half8 a = ldfrag(smem + W1FRAGO + (mi*64 + lane)*4);
      acc = __builtin_amdgcn_mfma_f32_32x32x16_f16(a, b1f, acc, 0, 0, 0);
#pragma unroll
      for (int p = 0; p < 8; ++p)
        pkA[mi][p] = pack_rtz(sw(acc[2*p]), sw(acc[2*p+1]));
    }

    // L2..L4 (ping-pong pkA/pkB, static chain)
    layer32(pkA, pkB, smem + WFRAG0, biasp + 128, h5, lane);
    layer32(pkB, pkA, smem + WFRAG1, biasp + 256, h5, lane);
    layer32(pkA, pkB, smem + WFRAG2, biasp + 384, h5, lane);

    // L5: out^T = W5^T @ h4^T + b5 (only rows 0,1 valid -> lanes h5==0, regs 0,1)
    f32x16 a5;
#pragma unroll
    for (int e = 0; e < 16; ++e) a5[e] = 0.f;
    a5[0] = b50; a5[1] = b51;
#pragma unroll
    for (int ks = 0; ks < 4; ++ks) {
      half8 bf0, bf1;
      build_b(pkB[ks], bf0, bf1);
      half8 a0 = ldfrag(smem + W5FRAGO + ((2*ks  )*64 + lane)*4);
      a5 = __builtin_amdgcn_mfma_f32_32x32x16_f16(a0, bf0, a5, 0, 0, 0);
      half8 a1 = ldfrag(smem + W5FRAGO + ((2*ks+1)*64 + lane)*4);
      a5 = __builtin_amdgcn_mfma_f32_32x32x16_f16(a1, bf1, a5, 0, 0, 0);
    }
    if (lo) {
      reinterpret_cast<float2*>(out)[s] = make_float2(a5[0], a5[1]);
    }
  }
}

extern "C" void kernel_launch(void* const* d_in, const int* in_sizes, int n_in,
                              void* d_out, int out_size, void* d_ws, size_t ws_size,
                              hipStream_t stream) {
  (void)in_sizes; (void)n_in; (void)d_ws; (void)ws_size; (void)out_size;
  const float* x  = (const float*)d_in[0];
  const float* t  = (const float*)d_in[1];
  const float* W1 = (const float*)d_in[2];
  const float* b1 = (const float*)d_in[3];
  const float* W2 = (const float*)d_in[4];
  const float* b2 = (const float*)d_in[5];
  const float* W3 = (const float*)d_in[6];
  const float* b3 = (const float*)d_in[7];
  const float* W4 = (const float*)d_in[8];
  const float* b4 = (const float*)d_in[9];
  const float* W5 = (const float*)d_in[10];
  const float* b5 = (const float*)d_in[11];
  float* out = (float*)d_out;

  mlp_k<<<dim3(NWG), dim3(WGSZ), 0, stream>>>(x, t, W1, b1, W2, b2, W3, b3, W4, b4, W5, b5, out);
}

// Round 9
// 258.505 us; speedup vs baseline: 4.3646x; 4.3646x over previous
//
#include <hip/hip_runtime.h>

typedef _Float16 half8  __attribute__((ext_vector_type(8)));
typedef __fp16   fp16x2 __attribute__((ext_vector_type(2)));
typedef float    f32x16 __attribute__((ext_vector_type(16)));
typedef float    f32x4v __attribute__((ext_vector_type(4)));
typedef unsigned uint2v __attribute__((ext_vector_type(2)));

#define NWG     256
#define WGSZ    512
#define CHUNKS  8          // samples per WG = CHUNKS*WGSZ = 4096; grid covers 1048576
// u32 offsets inside static LDS
#define WFRAG0   0         // W2 frags: 8192 u32 (128x128 f16, MFMA A-frag order)
#define WFRAG1   8192      // W3
#define WFRAG2   16384     // W4
#define W1FRAGO  24576     // 1024 u32
#define W5FRAGO  25600     // 2048 u32
#define BIASO    27648     // b1..b4: 4*128 f32
#define B5O      28160     // b5: 2 f32
#define SMEM_U32 28164     // 112656 B static LDS -> 1 WG/CU (2 waves/EU)

// Fence the instruction scheduler: r2-r8 all spilled ~1.6-2.3GB/dispatch to
// scratch despite ~100-reg source-level live sets, because the scheduler
// hoists LDS frag loads across the whole unrolled pass body (+100 regs of
// transient pressure) and the RA spills to its 128-VGPR cap. sched_barrier(0)
// at phase boundaries caps the hoisting scope.
#define FENCE() __builtin_amdgcn_sched_barrier(0)

__device__ __forceinline__ unsigned pack_rn(float a, float b) {
  unsigned lo = (unsigned)__builtin_bit_cast(unsigned short, (_Float16)a);
  unsigned hi = (unsigned)__builtin_bit_cast(unsigned short, (_Float16)b);
  return lo | (hi << 16);
}
__device__ __forceinline__ unsigned pack_rtz(float a, float b) {
  fp16x2 h = __builtin_amdgcn_cvt_pkrtz(a, b);
  return __builtin_bit_cast(unsigned, h);
}
// swish = v * sigmoid(v) = v * rcp(1 + 2^(-v*log2e)) : 3 VALU + 2 trans
__device__ __forceinline__ float sw(float v) {
  float e = __builtin_amdgcn_exp2f(v * -1.44269504089f);
  return v * __builtin_amdgcn_rcpf(1.0f + e);
}
__device__ __forceinline__ half8 ldfrag(const unsigned* p) {
  uint4 u = *reinterpret_cast<const uint4*>(p);
  return __builtin_bit_cast(half8, u);
}
__device__ __forceinline__ half8 mkfrag(unsigned a, unsigned b, unsigned c, unsigned d) {
  uint4 u = make_uint4(a, b, c, d);
  return __builtin_bit_cast(half8, u);
}

// permlane32_swap(a,b): a'[32+i]<->b[i]; result (a',b') =
//   a' = lanes<32: a       | lanes>=32: b[lane-32]   == (lo? a : shfl_xor(b,32))
//   b' = lanes<32: a[l+32] | lanes>=32: b            == (lo? shfl_xor(a,32) : b)
__device__ __forceinline__ void pl_swap(unsigned &a, unsigned &b) {
#if __has_builtin(__builtin_amdgcn_permlane32_swap)
  uint2v r = __builtin_amdgcn_permlane32_swap(a, b, false, false);
  a = r.x; b = r.y;
#else
  asm("v_permlane32_swap_b32 %0, %1" : "+v"(a), "+v"(b));
#endif
}

// Regroup packed D-frag (source frag ks) into the two B-frags for kk=2ks, 2ks+1.
__device__ __forceinline__ void build_b(const unsigned (&p)[8], half8 &bf0, half8 &bf1) {
  unsigned a0 = p[0], a2 = p[2];
  unsigned a1 = p[1], a3 = p[3];
  unsigned a4 = p[4], a6 = p[6];
  unsigned a5 = p[5], a7 = p[7];
  pl_swap(a0, a2);
  pl_swap(a1, a3);
  pl_swap(a4, a6);
  pl_swap(a5, a7);
  bf0 = mkfrag(a0, a1, a2, a3);
  bf1 = mkfrag(a4, a5, a6, a7);
}

// One 128x128 layer for 32 samples, one output-quarter (mi) at a time, with a
// scheduling fence after each quarter so transient pressure stays ~quarter-sized.
__device__ __forceinline__ void layer32(const unsigned (&pin)[4][8], unsigned (&pout)[4][8],
                                        const unsigned* wb, const float* bias, int h5, int lane) {
#pragma unroll
  for (int mi = 0; mi < 4; ++mi) {
    f32x16 acc;
    // bias: acc[4g+q] = bias[32mi + 8g + 4h5 + q]  (D-row map (r&3)+8(r>>2)+4h5)
#pragma unroll
    for (int g = 0; g < 4; ++g) {
      f32x4v bv = *reinterpret_cast<const f32x4v*>(bias + 32*mi + 8*g + 4*h5);
#pragma unroll
      for (int q = 0; q < 4; ++q) acc[4*g+q] = bv[q];
    }
#pragma unroll
    for (int ks = 0; ks < 4; ++ks) {
      half8 bf0, bf1;
      build_b(pin[ks], bf0, bf1);
      half8 a0 = ldfrag(wb + (((2*ks  )*4 + mi)*64 + lane)*4);
      acc = __builtin_amdgcn_mfma_f32_32x32x16_f16(a0, bf0, acc, 0, 0, 0);
      half8 a1 = ldfrag(wb + (((2*ks+1)*4 + mi)*64 + lane)*4);
      acc = __builtin_amdgcn_mfma_f32_32x32x16_f16(a1, bf1, acc, 0, 0, 0);
    }
    // swish + pack this quarter's output features
#pragma unroll
    for (int p = 0; p < 8; ++p)
      pout[mi][p] = pack_rtz(sw(acc[2*p]), sw(acc[2*p+1]));
    FENCE();
  }
}

extern "C" __global__ __launch_bounds__(WGSZ, 1)
void mlp_k(const float* __restrict__ x, const float* __restrict__ t,
           const float* __restrict__ W1, const float* __restrict__ b1,
           const float* __restrict__ W2, const float* __restrict__ b2,
           const float* __restrict__ W3, const float* __restrict__ b3,
           const float* __restrict__ W4, const float* __restrict__ b4,
           const float* __restrict__ W5, const float* __restrict__ b5p,
           float* __restrict__ out)
{
  __shared__ unsigned smem[SMEM_U32];
  const int tid = threadIdx.x;

  // ---------- stage weights (once per WG) ----------
  // mid layers: slot((kk,mi,lane,j2)) = pack(W[k][c], W[k+1][c]); k=16kk+8(lane>>5)+2j2, c=32mi+(lane&31)
  {
    const float* Wm[3] = {W2, W3, W4};
#pragma unroll
    for (int L = 0; L < 3; ++L) {
      const float* W = Wm[L];
#pragma unroll 1
      for (int it = 0; it < 16; ++it) {
        int i = it*WGSZ + tid;
        int lane = i & 63, j2 = (i >> 6) & 3, mi = (i >> 8) & 3, kk = i >> 10;
        int k = 16*kk + 8*(lane >> 5) + 2*j2;
        int c = 32*mi + (lane & 31);
        smem[L*8192 + ((kk*4 + mi)*64 + lane)*4 + j2] = pack_rn(W[k*128 + c], W[(k+1)*128 + c]);
      }
    }
  }
  // W1 (3x128), K padded to 16
#pragma unroll 1
  for (int it = 0; it < 2; ++it) {
    int i = it*WGSZ + tid;
    int lane = i & 63, j2 = (i >> 6) & 3, mi = (i >> 8) & 3;
    int k = 8*(lane >> 5) + 2*j2;
    int c = 32*mi + (lane & 31);
    float a = (k   < 3) ? W1[k*128 + c]     : 0.f;
    float b = (k+1 < 3) ? W1[(k+1)*128 + c] : 0.f;
    smem[W1FRAGO + (mi*64 + lane)*4 + j2] = pack_rn(a, b);
  }
  // W5 (128x2), M padded to 32 (rows >=2 are zero)
#pragma unroll 1
  for (int it = 0; it < 4; ++it) {
    int i = it*WGSZ + tid;
    int lane = i & 63, j2 = (i >> 6) & 3, kk = (i >> 8) & 7;
    int m = lane & 31;
    int k = 16*kk + 8*(lane >> 5) + 2*j2;
    float a = (m < 2) ? W5[k*2 + m]     : 0.f;
    float b = (m < 2) ? W5[(k+1)*2 + m] : 0.f;
    smem[W5FRAGO + (kk*64 + lane)*4 + j2] = pack_rn(a, b);
  }
  // biases
  {
    const float* bp = (tid < 128) ? b1 : (tid < 256) ? b2 : (tid < 384) ? b3 : b4;
    smem[BIASO + tid] = __builtin_bit_cast(unsigned, bp[tid & 127]);
    if (tid < 2) smem[B5O + tid] = __builtin_bit_cast(unsigned, b5p[tid]);
  }
  __syncthreads();

  // ---------- compute: no further barriers, waves free-run ----------
  const int lane = tid & 63;
  const int wv   = tid >> 6;
  const int h5   = lane >> 5;
  const int col  = lane & 31;
  const bool lo  = lane < 32;
  const float* biasp = reinterpret_cast<const float*>(smem + BIASO);
  const float b50 = reinterpret_cast<const float*>(smem + B5O)[0];
  const float b51 = reinterpret_cast<const float*>(smem + B5O)[1];
  const float2* x2 = reinterpret_cast<const float2*>(x);

  // 16 passes of 32 samples; phase fences keep scheduler pressure < 128 VGPRs.
#pragma unroll 1
  for (int ps = 0; ps < CHUNKS*2; ++ps) {
    const int base = ((int)blockIdx.x * CHUNKS + (ps >> 1)) * WGSZ + wv * 64 + 32*(ps & 1);
    const int s = base + col;

    float2 xa = x2[s];
    float  ta = t[s];

    // L1 B-operand: feats {x0,x1,t,0...} only in lanes h5==0, j<3
    half8 b1f = mkfrag(h5 ? 0u : pack_rn(xa.x, xa.y), h5 ? 0u : pack_rn(ta, 0.f), 0u, 0u);

    unsigned pkA[4][8], pkB[4][8];

    // L1: h1^T = W1^T @ [x;t]^T + b1 (quarter-at-a-time)
#pragma unroll
    for (int mi = 0; mi < 4; ++mi) {
      f32x16 acc;
#pragma unroll
      for (int g = 0; g < 4; ++g) {
        f32x4v bv = *reinterpret_cast<const f32x4v*>(biasp + 32*mi + 8*g + 4*h5);
#pragma unroll
        for (int q = 0; q < 4; ++q) acc[4*g+q] = bv[q];
      }
      half8 a = ldfrag(smem + W1FRAGO + (mi*64 + lane)*4);
      acc = __builtin_amdgcn_mfma_f32_32x32x16_f16(a, b1f, acc, 0, 0, 0);
#pragma unroll
      for (int p = 0; p < 8; ++p)
        pkA[mi][p] = pack_rtz(sw(acc[2*p]), sw(acc[2*p+1]));
      FENCE();
    }

    // L2..L4 (ping-pong pkA/pkB, static chain)
    layer32(pkA, pkB, smem + WFRAG0, biasp + 128, h5, lane);
    layer32(pkB, pkA, smem + WFRAG1, biasp + 256, h5, lane);
    layer32(pkA, pkB, smem + WFRAG2, biasp + 384, h5, lane);

    // L5: out^T = W5^T @ h4^T + b5 (only rows 0,1 valid -> lanes h5==0, regs 0,1)
    f32x16 a5;
#pragma unroll
    for (int e = 0; e < 16; ++e) a5[e] = 0.f;
    a5[0] = b50; a5[1] = b51;
#pragma unroll
    for (int ks = 0; ks < 4; ++ks) {
      half8 bf0, bf1;
      build_b(pkB[ks], bf0, bf1);
      half8 a0 = ldfrag(smem + W5FRAGO + ((2*ks  )*64 + lane)*4);
      a5 = __builtin_amdgcn_mfma_f32_32x32x16_f16(a0, bf0, a5, 0, 0, 0);
      half8 a1 = ldfrag(smem + W5FRAGO + ((2*ks+1)*64 + lane)*4);
      a5 = __builtin_amdgcn_mfma_f32_32x32x16_f16(a1, bf1, a5, 0, 0, 0);
    }
    if (lo) {
      reinterpret_cast<float2*>(out)[s] = make_float2(a5[0], a5[1]);
    }
    FENCE();
  }
}

extern "C" void kernel_launch(void* const* d_in, const int* in_sizes, int n_in,
                              void* d_out, int out_size, void* d_ws, size_t ws_size,
                              hipStream_t stream) {
  (void)in_sizes; (void)n_in; (void)d_ws; (void)ws_size; (void)out_size;
  const float* x  = (const float*)d_in[0];
  const float* t  = (const float*)d_in[1];
  const float* W1 = (const float*)d_in[2];
  const float* b1 = (const float*)d_in[3];
  const float* W2 = (const float*)d_in[4];
  const float* b2 = (const float*)d_in[5];
  const float* W3 = (const float*)d_in[6];
  const float* b3 = (const float*)d_in[7];
  const float* W4 = (const float*)d_in[8];
  const float* b4 = (const float*)d_in[9];
  const float* W5 = (const float*)d_in[10];
  const float* b5 = (const float*)d_in[11];
  float* out = (float*)d_out;

  mlp_k<<<dim3(NWG), dim3(WGSZ), 0, stream>>>(x, t, W1, b1, W2, b2, W3, b3, W4, b4, W5, b5, out);
}